// Round 1
// baseline (791.364 us; speedup 1.0000x reference)
//
#include <hip/hip_runtime.h>
#include <hip/hip_bf16.h>
#include <cstdint>
#include <cstddef>

// Problem constants
#define B_ROWS 32768
#define DIM    256
#define N_CB   8192
#define NBLK   256          // 32-wide column blocks per row (8192/32)
#define MARGIN 8e-3f        // provable bound: 2 * 2^-8 * ||a||*||b|| = 7.8e-3 (RNE bf16)

typedef __bf16 bf16x8 __attribute__((ext_vector_type(8)));
typedef float  f32x4  __attribute__((ext_vector_type(4)));

// ---- workspace layout (bytes) ----
#define WS_XBF      ((size_t)0)                    // 32768*256*2 = 16 MB
#define WS_CBBF     ((size_t)16777216)             //  8192*256*2 =  4 MB
#define WS_BLOCKMAX ((size_t)20971520)             // 32768*256*4 = 32 MB
#define WS_CNORM    ((size_t)54525952)             //  8192*8     = 64 KB
#define WS_BESTIDX  ((size_t)54591488)             // 32768*4     = 128 KB
#define WS_LOSS     ((size_t)54722560)             // 4 B   (total ~54.7 MB)

// ---- output layout (floats, concatenated in return order) ----
#define OUT_XQ   ((size_t)0)
#define OUT_LOSS ((size_t)8388608)
#define OUT_IDX  ((size_t)8388609)
#define OUT_SCAL ((size_t)(8388609 + 32768))

__device__ inline float wave_sum(float v)   { for (int d = 1; d < 64; d <<= 1) v += __shfl_xor(v, d); return v; }
__device__ inline double wave_sum_d(double v){ for (int d = 1; d < 64; d <<= 1) v += __shfl_xor(v, d); return v; }
__device__ inline float wave_max(float v)   { for (int d = 1; d < 64; d <<= 1) v = fmaxf(v, __shfl_xor(v, d)); return v; }

// Manual round-to-nearest-even f32 -> bf16 so the filter error bound holds (|rel| <= 2^-9).
__device__ inline ushort f2bf(float f) {
    unsigned u = __float_as_uint(f);
    unsigned r = (u + 0x7fffu + ((u >> 16) & 1u)) >> 16;
    return (ushort)r;
}

__device__ inline void load16_lds(const void* g, void* l) {
    __builtin_amdgcn_global_load_lds(
        (const __attribute__((address_space(1))) unsigned int*)g,
        (__attribute__((address_space(3))) unsigned int*)l, 16, 0, 0);
}

// ---------------------------------------------------------------------------
// Phase 0: per-row L2 norms, bf16 normalized copies, fp64 codebook norms.
// One wave per row; rows [0,32768) = x, [32768, 40960) = codebook.
// ---------------------------------------------------------------------------
__global__ __launch_bounds__(256)
void prep_kernel(const float* __restrict__ x, const float* __restrict__ cb,
                 ushort* __restrict__ xbf, ushort* __restrict__ cbbf,
                 double* __restrict__ cnorm, float* __restrict__ loss_acc) {
    if (blockIdx.x == 0 && threadIdx.x == 0) *loss_acc = 0.f;
    int gw   = blockIdx.x * 4 + (threadIdx.x >> 6);
    int lane = threadIdx.x & 63;
    bool is_cb = gw >= B_ROWS;
    int row  = is_cb ? gw - B_ROWS : gw;
    const float* src = is_cb ? cb + (size_t)row * DIM : x + (size_t)row * DIM;
    ushort*      dst = is_cb ? cbbf + (size_t)row * DIM : xbf + (size_t)row * DIM;

    float4 v = ((const float4*)src)[lane];
    double ss = (double)v.x * v.x + (double)v.y * v.y + (double)v.z * v.z + (double)v.w * v.w;
    ss = wave_sum_d(ss);
    float inv = 1.f / fmaxf(sqrtf((float)ss), 1e-12f);
    ushort4 o;
    o.x = f2bf(v.x * inv); o.y = f2bf(v.y * inv);
    o.z = f2bf(v.z * inv); o.w = f2bf(v.w * inv);
    ((ushort4*)dst)[lane] = o;
    if (is_cb && lane == 0) cnorm[row] = sqrt(ss);
}

// ---------------------------------------------------------------------------
// Phase 1: bf16 MFMA "GEMM" producing per-(row, 32-col-block) sim maxes.
// m97 structure: 128x128 tile, BK=64, global_load_lds(16B), 16x16x32 MFMA,
// 256 threads = 4 waves in a 2x2 grid (each wave owns a 64x64 quadrant).
// ---------------------------------------------------------------------------
__global__ __launch_bounds__(256, 2)
void simmax_kernel(const ushort* __restrict__ xbf, const ushort* __restrict__ cbbf,
                   float* __restrict__ blockmax) {
    __shared__ __align__(16) ushort As[128 * 64];
    __shared__ __align__(16) ushort Bs[128 * 64];
    const int t   = threadIdx.x;
    const int rm0 = blockIdx.x * 128;          // row-tile   (x rows)
    const int by  = blockIdx.y;
    const int cn0 = by * 128;                  // col-tile   (codebook rows)
    const int wid = t >> 6, lane = t & 63;
    const int wy = wid >> 1, wx = wid & 1;
    const int q = lane >> 4, r16 = lane & 15;

    f32x4 acc[4][4];
#pragma unroll
    for (int i = 0; i < 4; i++)
#pragma unroll
        for (int j = 0; j < 4; j++) acc[i][j] = (f32x4){0.f, 0.f, 0.f, 0.f};

    const int srow = t >> 3;          // staging: thread t covers 16B at tile byte t*16
    const int scol = (t & 7) * 8;     // element (bf16) offset within BK=64

#pragma unroll
    for (int ks = 0; ks < 4; ++ks) {
        const int k0 = ks * 64;
#pragma unroll
        for (int it = 0; it < 4; ++it) {
            const int row = it * 32 + srow;
            const int ldsoff = row * 64 + scol;          // ushort elements
            load16_lds(xbf  + (size_t)(rm0 + row) * DIM + k0 + scol, As + ldsoff);
            load16_lds(cbbf + (size_t)(cn0 + row) * DIM + k0 + scol, Bs + ldsoff);
        }
        __syncthreads();   // compiler emits s_waitcnt vmcnt(0) before s_barrier
#pragma unroll
        for (int kk = 0; kk < 2; ++kk) {
            bf16x8 af[4], bfr[4];
#pragma unroll
            for (int ii = 0; ii < 4; ii++) {
                int r = wy * 64 + ii * 16 + r16;
                af[ii] = *(const bf16x8*)(As + r * 64 + kk * 32 + q * 8);
            }
#pragma unroll
            for (int jj = 0; jj < 4; jj++) {
                int c = wx * 64 + jj * 16 + r16;
                bfr[jj] = *(const bf16x8*)(Bs + c * 64 + kk * 32 + q * 8);
            }
#pragma unroll
            for (int ii = 0; ii < 4; ii++)
#pragma unroll
                for (int jj = 0; jj < 4; jj++)
                    acc[ii][jj] = __builtin_amdgcn_mfma_f32_16x16x32_bf16(
                        af[ii], bfr[jj], acc[ii][jj], 0, 0, 0);
        }
        __syncthreads();
    }

    // Epilogue: C/D layout col=lane&15, row=q*4+reg. Reduce max over 32-col blocks.
#pragma unroll
    for (int ii = 0; ii < 4; ii++) {
#pragma unroll
        for (int jjp = 0; jjp < 2; jjp++) {
            float v[4];
#pragma unroll
            for (int r = 0; r < 4; r++)
                v[r] = fmaxf(acc[ii][2 * jjp][r], acc[ii][2 * jjp + 1][r]);
#pragma unroll
            for (int d = 1; d < 16; d <<= 1)
#pragma unroll
                for (int r = 0; r < 4; r++) v[r] = fmaxf(v[r], __shfl_xor(v[r], d));
            if (r16 == 0) {
                int blk = by * 4 + wx * 2 + jjp;
#pragma unroll
                for (int r = 0; r < 4; r++) {
                    int row = rm0 + wy * 64 + ii * 16 + q * 4 + r;
                    blockmax[(size_t)row * NBLK + blk] = v[r];
                }
            }
        }
    }
}

// ---------------------------------------------------------------------------
// Phase 2: exact argmax. One wave per row. Candidate blocks within MARGIN of
// the approx rowmax get all 32 candidates re-evaluated in fp64 on the
// ORIGINAL fp32 data (dividing by fp64 codebook norm; the row norm is a
// positive row-constant and cannot change the argmax).
// ---------------------------------------------------------------------------
__global__ __launch_bounds__(256)
void argmax_kernel(const float* __restrict__ x, const float* __restrict__ cb,
                   const float* __restrict__ blockmax, const double* __restrict__ cnorm,
                   int* __restrict__ best_idx) {
    int row  = blockIdx.x * 4 + (threadIdx.x >> 6);
    int lane = threadIdx.x & 63;
    float4 b4 = ((const float4*)(blockmax + (size_t)row * NBLK))[lane];
    float m = fmaxf(fmaxf(b4.x, b4.y), fmaxf(b4.z, b4.w));
    float rowmax = wave_max(m);
    float thr = rowmax - MARGIN;

    float4 xr = ((const float4*)(x + (size_t)row * DIM))[lane];
    double x0 = xr.x, x1 = xr.y, x2 = xr.z, x3 = xr.w;

    double best_s = -1e300;
    int best_i = 0x7fffffff;
    float bmv[4] = {b4.x, b4.y, b4.z, b4.w};
#pragma unroll
    for (int j = 0; j < 4; j++) {
        unsigned long long mask = __ballot(bmv[j] >= thr);
        while (mask) {
            int src = __ffsll((unsigned long long)mask) - 1;
            mask &= mask - 1;
            int nbase = (src * 4 + j) * 32;
            for (int c = 0; c < 32; c++) {
                int n = nbase + c;
                float4 cv = ((const float4*)(cb + (size_t)n * DIM))[lane];
                double s = x0 * cv.x + x1 * cv.y + x2 * cv.z + x3 * cv.w;
                s = wave_sum_d(s);
                s = s / cnorm[n];
                if (s > best_s || (s == best_s && n < best_i)) { best_s = s; best_i = n; }
            }
        }
    }
    if (lane == 0) best_idx[row] = best_i;
}

// ---------------------------------------------------------------------------
// Phase 3: gather + scalar + proj + x_q + commit-loss accumulation.
// ---------------------------------------------------------------------------
__global__ __launch_bounds__(256)
void finalize_kernel(const float* __restrict__ x, const float* __restrict__ cb,
                     const int* __restrict__ best_idx, float* __restrict__ out,
                     float* __restrict__ loss_acc) {
    __shared__ float lsum[4];
    int w    = threadIdx.x >> 6;
    int row  = blockIdx.x * 4 + w;
    int lane = threadIdx.x & 63;
    int idx  = best_idx[row];
    float4 xv = ((const float4*)(x + (size_t)row * DIM))[lane];
    float4 cv = ((const float4*)(cb + (size_t)idx * DIM))[lane];
    float dot = xv.x * cv.x + xv.y * cv.y + xv.z * cv.z + xv.w * cv.w;
    float nsq = cv.x * cv.x + cv.y * cv.y + cv.z * cv.z + cv.w * cv.w;
    float xsq = xv.x * xv.x + xv.y * xv.y + xv.z * xv.z + xv.w * xv.w;
    for (int d = 1; d < 64; d <<= 1) {
        dot += __shfl_xor(dot, d);
        nsq += __shfl_xor(nsq, d);
        xsq += __shfl_xor(xsq, d);
    }
    float scalar = dot / (nsq + 1e-8f);
    float4 pj = {scalar * cv.x, scalar * cv.y, scalar * cv.z, scalar * cv.w};
    ((float4*)(out + OUT_XQ + (size_t)row * DIM))[lane] = pj;

    float pn = fmaxf(sqrtf(scalar * scalar * nsq), 1e-8f);
    float xn = fmaxf(sqrtf(xsq), 1e-8f);
    float commit = (scalar * dot) / (pn * xn);
    if (lane == 0) {
        lsum[w] = 1.f - commit;
        out[OUT_IDX + row]  = (float)idx;
        out[OUT_SCAL + row] = scalar;
    }
    __syncthreads();
    if (threadIdx.x == 0)
        atomicAdd(loss_acc, lsum[0] + lsum[1] + lsum[2] + lsum[3]);
}

__global__ void loss_kernel(const float* __restrict__ loss_acc, float* __restrict__ out) {
    out[OUT_LOSS] = 0.25f * (*loss_acc) * (1.0f / 32768.0f);
}

// ---------------------------------------------------------------------------
extern "C" void kernel_launch(void* const* d_in, const int* in_sizes, int n_in,
                              void* d_out, int out_size, void* d_ws, size_t ws_size,
                              hipStream_t stream) {
    const float* x  = (const float*)d_in[0];
    const float* cb = (const float*)d_in[1];
    float* out = (float*)d_out;
    char*  ws  = (char*)d_ws;
    ushort* xbf      = (ushort*)(ws + WS_XBF);
    ushort* cbbf     = (ushort*)(ws + WS_CBBF);
    float*  blockmax = (float*)(ws + WS_BLOCKMAX);
    double* cnorm    = (double*)(ws + WS_CNORM);
    int*    best_idx = (int*)(ws + WS_BESTIDX);
    float*  loss_acc = (float*)(ws + WS_LOSS);

    hipLaunchKernelGGL(prep_kernel, dim3((B_ROWS + N_CB) / 4), dim3(256), 0, stream,
                       x, cb, xbf, cbbf, cnorm, loss_acc);
    hipLaunchKernelGGL(simmax_kernel, dim3(B_ROWS / 128, N_CB / 128), dim3(256), 0, stream,
                       xbf, cbbf, blockmax);
    hipLaunchKernelGGL(argmax_kernel, dim3(B_ROWS / 4), dim3(256), 0, stream,
                       x, cb, blockmax, cnorm, best_idx);
    hipLaunchKernelGGL(finalize_kernel, dim3(B_ROWS / 4), dim3(256), 0, stream,
                       x, cb, best_idx, out, loss_acc);
    hipLaunchKernelGGL(loss_kernel, dim3(1), dim3(1), 0, stream, loss_acc, out);
}

// Round 2
// 688.103 us; speedup vs baseline: 1.1501x; 1.1501x over previous
//
#include <hip/hip_runtime.h>
#include <hip/hip_bf16.h>
#include <cstdint>
#include <cstddef>

// Problem constants
#define B_ROWS 32768
#define DIM    256
#define N_CB   8192
#define NBLK   256          // 32-wide column blocks per row (8192/32)
#define MARGIN 8e-3f        // provable bound: 2 * 2^-8 * ||a||*||b|| = 7.8e-3 (RNE bf16)

typedef __bf16 bf16x8 __attribute__((ext_vector_type(8)));
typedef float  f32x4  __attribute__((ext_vector_type(4)));

// ---- workspace layout (bytes) ----
#define WS_XBF      ((size_t)0)                    // 32768*256*2 = 16 MB
#define WS_CBBF     ((size_t)16777216)             //  8192*256*2 =  4 MB
#define WS_BLOCKMAX ((size_t)20971520)             // 32768*256*4 = 32 MB
#define WS_CNORM    ((size_t)54525952)             //  8192*8     = 64 KB (inv norms, fp64)
#define WS_BESTIDX  ((size_t)54591488)             // 32768*4     = 128 KB
#define WS_LOSS     ((size_t)54722560)             // 4 B   (total ~54.7 MB)

// ---- output layout (floats, concatenated in return order) ----
#define OUT_XQ   ((size_t)0)
#define OUT_LOSS ((size_t)8388608)
#define OUT_IDX  ((size_t)8388609)
#define OUT_SCAL ((size_t)(8388609 + 32768))

__device__ inline double wave_sum_d(double v){ for (int d = 1; d < 64; d <<= 1) v += __shfl_xor(v, d); return v; }
__device__ inline float wave_max(float v)   { for (int d = 1; d < 64; d <<= 1) v = fmaxf(v, __shfl_xor(v, d)); return v; }

// Manual round-to-nearest-even f32 -> bf16 so the filter error bound holds (|rel| <= 2^-9).
__device__ inline ushort f2bf(float f) {
    unsigned u = __float_as_uint(f);
    unsigned r = (u + 0x7fffu + ((u >> 16) & 1u)) >> 16;
    return (ushort)r;
}

__device__ inline void load16_lds(const void* g, void* l) {
    __builtin_amdgcn_global_load_lds(
        (const __attribute__((address_space(1))) unsigned int*)g,
        (__attribute__((address_space(3))) unsigned int*)l, 16, 0, 0);
}

// ---------------------------------------------------------------------------
// Phase 0: per-row L2 norms, bf16 normalized copies, fp64 inverse codebook norms.
// One wave per row; rows [0,32768) = x, [32768, 40960) = codebook.
// ---------------------------------------------------------------------------
__global__ __launch_bounds__(256)
void prep_kernel(const float* __restrict__ x, const float* __restrict__ cb,
                 ushort* __restrict__ xbf, ushort* __restrict__ cbbf,
                 double* __restrict__ inv_cnorm, float* __restrict__ loss_acc) {
    if (blockIdx.x == 0 && threadIdx.x == 0) *loss_acc = 0.f;
    int gw   = blockIdx.x * 4 + (threadIdx.x >> 6);
    int lane = threadIdx.x & 63;
    bool is_cb = gw >= B_ROWS;
    int row  = is_cb ? gw - B_ROWS : gw;
    const float* src = is_cb ? cb + (size_t)row * DIM : x + (size_t)row * DIM;
    ushort*      dst = is_cb ? cbbf + (size_t)row * DIM : xbf + (size_t)row * DIM;

    float4 v = ((const float4*)src)[lane];
    double ss = (double)v.x * v.x + (double)v.y * v.y + (double)v.z * v.z + (double)v.w * v.w;
    ss = wave_sum_d(ss);
    float inv = 1.f / fmaxf(sqrtf((float)ss), 1e-12f);
    ushort4 o;
    o.x = f2bf(v.x * inv); o.y = f2bf(v.y * inv);
    o.z = f2bf(v.z * inv); o.w = f2bf(v.w * inv);
    ((ushort4*)dst)[lane] = o;
    if (is_cb && lane == 0) inv_cnorm[row] = 1.0 / sqrt(ss);
}

// ---------------------------------------------------------------------------
// Phase 1: bf16 MFMA "GEMM" producing per-(row, 32-col-block) sim maxes.
// m97 structure: 128x128 tile, BK=64, global_load_lds(16B), 16x16x32 MFMA,
// 256 threads = 4 waves in a 2x2 grid (each wave owns a 64x64 quadrant).
// ---------------------------------------------------------------------------
__global__ __launch_bounds__(256, 2)
void simmax_kernel(const ushort* __restrict__ xbf, const ushort* __restrict__ cbbf,
                   float* __restrict__ blockmax) {
    __shared__ __align__(16) ushort As[128 * 64];
    __shared__ __align__(16) ushort Bs[128 * 64];
    const int t   = threadIdx.x;
    const int rm0 = blockIdx.x * 128;          // row-tile   (x rows)
    const int by  = blockIdx.y;
    const int cn0 = by * 128;                  // col-tile   (codebook rows)
    const int wid = t >> 6, lane = t & 63;
    const int wy = wid >> 1, wx = wid & 1;
    const int q = lane >> 4, r16 = lane & 15;

    f32x4 acc[4][4];
#pragma unroll
    for (int i = 0; i < 4; i++)
#pragma unroll
        for (int j = 0; j < 4; j++) acc[i][j] = (f32x4){0.f, 0.f, 0.f, 0.f};

    const int srow = t >> 3;          // staging: thread t covers 16B at tile byte t*16
    const int scol = (t & 7) * 8;     // element (bf16) offset within BK=64

#pragma unroll
    for (int ks = 0; ks < 4; ++ks) {
        const int k0 = ks * 64;
#pragma unroll
        for (int it = 0; it < 4; ++it) {
            const int row = it * 32 + srow;
            const int ldsoff = row * 64 + scol;          // ushort elements
            load16_lds(xbf  + (size_t)(rm0 + row) * DIM + k0 + scol, As + ldsoff);
            load16_lds(cbbf + (size_t)(cn0 + row) * DIM + k0 + scol, Bs + ldsoff);
        }
        __syncthreads();
#pragma unroll
        for (int kk = 0; kk < 2; ++kk) {
            bf16x8 af[4], bfr[4];
#pragma unroll
            for (int ii = 0; ii < 4; ii++) {
                int r = wy * 64 + ii * 16 + r16;
                af[ii] = *(const bf16x8*)(As + r * 64 + kk * 32 + q * 8);
            }
#pragma unroll
            for (int jj = 0; jj < 4; jj++) {
                int c = wx * 64 + jj * 16 + r16;
                bfr[jj] = *(const bf16x8*)(Bs + c * 64 + kk * 32 + q * 8);
            }
#pragma unroll
            for (int ii = 0; ii < 4; ii++)
#pragma unroll
                for (int jj = 0; jj < 4; jj++)
                    acc[ii][jj] = __builtin_amdgcn_mfma_f32_16x16x32_bf16(
                        af[ii], bfr[jj], acc[ii][jj], 0, 0, 0);
        }
        __syncthreads();
    }

    // Epilogue: C/D layout col=lane&15, row=q*4+reg. Reduce max over 32-col blocks.
#pragma unroll
    for (int ii = 0; ii < 4; ii++) {
#pragma unroll
        for (int jjp = 0; jjp < 2; jjp++) {
            float v[4];
#pragma unroll
            for (int r = 0; r < 4; r++)
                v[r] = fmaxf(acc[ii][2 * jjp][r], acc[ii][2 * jjp + 1][r]);
#pragma unroll
            for (int d = 1; d < 16; d <<= 1)
#pragma unroll
                for (int r = 0; r < 4; r++) v[r] = fmaxf(v[r], __shfl_xor(v[r], d));
            if (r16 == 0) {
                int blk = by * 4 + wx * 2 + jjp;
#pragma unroll
                for (int r = 0; r < 4; r++) {
                    int row = rm0 + wy * 64 + ii * 16 + q * 4 + r;
                    blockmax[(size_t)row * NBLK + blk] = v[r];
                }
            }
        }
    }
}

// ---------------------------------------------------------------------------
// Phase 2: exact argmax, lane-per-candidate. One wave per row. Candidate
// blocks within MARGIN of the approx rowmax are processed two at a time:
// each lane owns one candidate and computes a full fp64 dot on the ORIGINAL
// fp32 data (times fp64 inverse codebook norm; the x-row norm is a positive
// row-constant and cannot change the argmax). One wave argmax-reduce per row.
// ---------------------------------------------------------------------------
__global__ __launch_bounds__(256)
void argmax_kernel(const float* __restrict__ x, const float* __restrict__ cb,
                   const float* __restrict__ blockmax, const double* __restrict__ inv_cnorm,
                   int* __restrict__ best_idx) {
    __shared__ float4 xs[4][64];
    const int w    = threadIdx.x >> 6;
    const int row  = blockIdx.x * 4 + w;
    const int lane = threadIdx.x & 63;

    // stage this wave's x row in LDS (read back as uniform-address broadcasts)
    xs[w][lane] = ((const float4*)(x + (size_t)row * DIM))[lane];

    float4 b4 = ((const float4*)(blockmax + (size_t)row * NBLK))[lane];
    float m = fmaxf(fmaxf(b4.x, b4.y), fmaxf(b4.z, b4.w));
    float rowmax = wave_max(m);
    float thr = rowmax - MARGIN;

    double best_s = -1e300;
    int best_i = 0x7fffffff;

    auto eval_pair = [&](int bA, int bB) {
        int n = -1;
        if (lane < 32) n = bA * 32 + lane;
        else if (bB >= 0) n = bB * 32 + (lane - 32);
        if (n >= 0) {
            const float4* crow = (const float4*)(cb + (size_t)n * DIM);
            double s0 = 0., s1 = 0., s2 = 0., s3 = 0.;
#pragma unroll 8
            for (int jj = 0; jj < 64; ++jj) {
                float4 xv = xs[w][jj];
                float4 cv = crow[jj];
                s0 = fma((double)xv.x, (double)cv.x, s0);
                s1 = fma((double)xv.y, (double)cv.y, s1);
                s2 = fma((double)xv.z, (double)cv.z, s2);
                s3 = fma((double)xv.w, (double)cv.w, s3);
            }
            double s = ((s0 + s1) + (s2 + s3)) * inv_cnorm[n];
            if (s > best_s || (s == best_s && n < best_i)) { best_s = s; best_i = n; }
        }
    };

    float bmv[4] = {b4.x, b4.y, b4.z, b4.w};
    int pend = -1;
#pragma unroll
    for (int j = 0; j < 4; j++) {
        unsigned long long mask = __ballot(bmv[j] >= thr);   // wave-uniform
        while (mask) {
            int src = __ffsll((unsigned long long)mask) - 1;
            mask &= mask - 1;
            int blk = src * 4 + j;
            if (pend < 0) pend = blk;
            else { eval_pair(pend, blk); pend = -1; }
        }
    }
    if (pend >= 0) eval_pair(pend, -1);

    // wave argmax (value desc, index asc tiebreak)
    for (int d = 1; d < 64; d <<= 1) {
        double os = __shfl_xor(best_s, d);
        int    oi = __shfl_xor(best_i, d);
        if (os > best_s || (os == best_s && oi < best_i)) { best_s = os; best_i = oi; }
    }
    if (lane == 0) best_idx[row] = best_i;
}

// ---------------------------------------------------------------------------
// Phase 3: gather + scalar + proj + x_q + commit-loss accumulation.
// ---------------------------------------------------------------------------
__global__ __launch_bounds__(256)
void finalize_kernel(const float* __restrict__ x, const float* __restrict__ cb,
                     const int* __restrict__ best_idx, float* __restrict__ out,
                     float* __restrict__ loss_acc) {
    __shared__ float lsum[4];
    int w    = threadIdx.x >> 6;
    int row  = blockIdx.x * 4 + w;
    int lane = threadIdx.x & 63;
    int idx  = best_idx[row];
    float4 xv = ((const float4*)(x + (size_t)row * DIM))[lane];
    float4 cv = ((const float4*)(cb + (size_t)idx * DIM))[lane];
    float dot = xv.x * cv.x + xv.y * cv.y + xv.z * cv.z + xv.w * cv.w;
    float nsq = cv.x * cv.x + cv.y * cv.y + cv.z * cv.z + cv.w * cv.w;
    float xsq = xv.x * xv.x + xv.y * xv.y + xv.z * xv.z + xv.w * xv.w;
    for (int d = 1; d < 64; d <<= 1) {
        dot += __shfl_xor(dot, d);
        nsq += __shfl_xor(nsq, d);
        xsq += __shfl_xor(xsq, d);
    }
    float scalar = dot / (nsq + 1e-8f);
    float4 pj = {scalar * cv.x, scalar * cv.y, scalar * cv.z, scalar * cv.w};
    ((float4*)(out + OUT_XQ + (size_t)row * DIM))[lane] = pj;

    float pn = fmaxf(sqrtf(scalar * scalar * nsq), 1e-8f);
    float xn = fmaxf(sqrtf(xsq), 1e-8f);
    float commit = (scalar * dot) / (pn * xn);
    if (lane == 0) {
        lsum[w] = 1.f - commit;
        out[OUT_IDX + row]  = (float)idx;
        out[OUT_SCAL + row] = scalar;
    }
    __syncthreads();
    if (threadIdx.x == 0)
        atomicAdd(loss_acc, lsum[0] + lsum[1] + lsum[2] + lsum[3]);
}

__global__ void loss_kernel(const float* __restrict__ loss_acc, float* __restrict__ out) {
    out[OUT_LOSS] = 0.25f * (*loss_acc) * (1.0f / 32768.0f);
}

// ---------------------------------------------------------------------------
extern "C" void kernel_launch(void* const* d_in, const int* in_sizes, int n_in,
                              void* d_out, int out_size, void* d_ws, size_t ws_size,
                              hipStream_t stream) {
    const float* x  = (const float*)d_in[0];
    const float* cb = (const float*)d_in[1];
    float* out = (float*)d_out;
    char*  ws  = (char*)d_ws;
    ushort* xbf      = (ushort*)(ws + WS_XBF);
    ushort* cbbf     = (ushort*)(ws + WS_CBBF);
    float*  blockmax = (float*)(ws + WS_BLOCKMAX);
    double* inv_cn   = (double*)(ws + WS_CNORM);
    int*    best_idx = (int*)(ws + WS_BESTIDX);
    float*  loss_acc = (float*)(ws + WS_LOSS);

    hipLaunchKernelGGL(prep_kernel, dim3((B_ROWS + N_CB) / 4), dim3(256), 0, stream,
                       x, cb, xbf, cbbf, inv_cn, loss_acc);
    hipLaunchKernelGGL(simmax_kernel, dim3(B_ROWS / 128, N_CB / 128), dim3(256), 0, stream,
                       xbf, cbbf, blockmax);
    hipLaunchKernelGGL(argmax_kernel, dim3(B_ROWS / 4), dim3(256), 0, stream,
                       x, cb, blockmax, inv_cn, best_idx);
    hipLaunchKernelGGL(finalize_kernel, dim3(B_ROWS / 4), dim3(256), 0, stream,
                       x, cb, best_idx, out, loss_acc);
    hipLaunchKernelGGL(loss_kernel, dim3(1), dim3(1), 0, stream, loss_acc, out);
}

// Round 3
// 686.315 us; speedup vs baseline: 1.1531x; 1.0026x over previous
//
#include <hip/hip_runtime.h>
#include <hip/hip_bf16.h>
#include <cstdint>
#include <cstddef>

// Problem constants
#define B_ROWS 32768
#define DIM    256
#define N_CB   8192
#define NBLK   256          // 32-wide column blocks per row (8192/32)
#define MARGIN 8e-3f        // provable bound: 2 * 2^-8 * ||a||*||b|| = 7.8e-3 (RNE bf16)

typedef __bf16 bf16x8 __attribute__((ext_vector_type(8)));
typedef float  f32x4  __attribute__((ext_vector_type(4)));

// ---- workspace layout (bytes) ----
#define WS_XBF      ((size_t)0)                    // 32768*256*2 = 16 MB
#define WS_CBBF     ((size_t)16777216)             //  8192*256*2 =  4 MB
#define WS_BLOCKMAX ((size_t)20971520)             // 32768*256*4 = 32 MB
#define WS_CNORM    ((size_t)54525952)             //  8192*8     = 64 KB (inv norms, fp64)
#define WS_BESTIDX  ((size_t)54591488)             // 32768*4     = 128 KB
#define WS_LOSS     ((size_t)54722560)             // 4 B   (total ~54.7 MB)

// ---- output layout (floats, concatenated in return order) ----
#define OUT_XQ   ((size_t)0)
#define OUT_LOSS ((size_t)8388608)
#define OUT_IDX  ((size_t)8388609)
#define OUT_SCAL ((size_t)(8388609 + 32768))

__device__ inline double wave_sum_d(double v){ for (int d = 1; d < 64; d <<= 1) v += __shfl_xor(v, d); return v; }
__device__ inline float wave_max(float v)   { for (int d = 1; d < 64; d <<= 1) v = fmaxf(v, __shfl_xor(v, d)); return v; }

// Manual round-to-nearest-even f32 -> bf16 so the filter error bound holds (|rel| <= 2^-9).
__device__ inline ushort f2bf(float f) {
    unsigned u = __float_as_uint(f);
    unsigned r = (u + 0x7fffu + ((u >> 16) & 1u)) >> 16;
    return (ushort)r;
}

__device__ inline void load16_lds(const void* g, void* l) {
    __builtin_amdgcn_global_load_lds(
        (const __attribute__((address_space(1))) unsigned int*)g,
        (__attribute__((address_space(3))) unsigned int*)l, 16, 0, 0);
}

// ---------------------------------------------------------------------------
// Phase 0: per-row L2 norms, bf16 normalized copies, fp64 inverse codebook norms.
// ---------------------------------------------------------------------------
__global__ __launch_bounds__(256)
void prep_kernel(const float* __restrict__ x, const float* __restrict__ cb,
                 ushort* __restrict__ xbf, ushort* __restrict__ cbbf,
                 double* __restrict__ inv_cnorm, float* __restrict__ loss_acc) {
    if (blockIdx.x == 0 && threadIdx.x == 0) *loss_acc = 0.f;
    int gw   = blockIdx.x * 4 + (threadIdx.x >> 6);
    int lane = threadIdx.x & 63;
    bool is_cb = gw >= B_ROWS;
    int row  = is_cb ? gw - B_ROWS : gw;
    const float* src = is_cb ? cb + (size_t)row * DIM : x + (size_t)row * DIM;
    ushort*      dst = is_cb ? cbbf + (size_t)row * DIM : xbf + (size_t)row * DIM;

    float4 v = ((const float4*)src)[lane];
    double ss = (double)v.x * v.x + (double)v.y * v.y + (double)v.z * v.z + (double)v.w * v.w;
    ss = wave_sum_d(ss);
    float inv = 1.f / fmaxf(sqrtf((float)ss), 1e-12f);
    ushort4 o;
    o.x = f2bf(v.x * inv); o.y = f2bf(v.y * inv);
    o.z = f2bf(v.z * inv); o.w = f2bf(v.w * inv);
    ((ushort4*)dst)[lane] = o;
    if (is_cb && lane == 0) inv_cnorm[row] = 1.0 / sqrt(ss);
}

// ---------------------------------------------------------------------------
// Phase 1: bf16 MFMA "GEMM" producing per-(row, 32-col-block) sim maxes.
// m97 structure + XOR-swizzled LDS: chunk-position p of row r holds global
// 16B-chunk (p ^ (r&7)). Any 8 consecutive lanes of a fragment ds_read_b128
// then cover all 32 banks exactly once -> conflict-free (m136).
// ---------------------------------------------------------------------------
__global__ __launch_bounds__(256, 2)
void simmax_kernel(const ushort* __restrict__ xbf, const ushort* __restrict__ cbbf,
                   float* __restrict__ blockmax) {
    __shared__ __align__(16) ushort As[128 * 64];
    __shared__ __align__(16) ushort Bs[128 * 64];
    const int t   = threadIdx.x;
    const int rm0 = blockIdx.x * 128;          // row-tile   (x rows)
    const int by  = blockIdx.y;
    const int cn0 = by * 128;                  // col-tile   (codebook rows)
    const int wid = t >> 6, lane = t & 63;
    const int wy = wid >> 1, wx = wid & 1;
    const int q = lane >> 4, r16 = lane & 15;

    f32x4 acc[4][4];
#pragma unroll
    for (int i = 0; i < 4; i++)
#pragma unroll
        for (int j = 0; j < 4; j++) acc[i][j] = (f32x4){0.f, 0.f, 0.f, 0.f};

    const int srow     = t >> 3;                            // row within 32-row group
    const int cpos     = t & 7;                             // LDS chunk position
    const int csrc     = cpos ^ (srow & 7);                 // swizzled global chunk
    const int scol_src = csrc * 8;                          // global element offset
    const int scol_lds = cpos * 8;                          // LDS element offset

#pragma unroll
    for (int ks = 0; ks < 4; ++ks) {
        const int k0 = ks * 64;
#pragma unroll
        for (int it = 0; it < 4; ++it) {
            const int row = it * 32 + srow;
            const int ldsoff = row * 64 + scol_lds;          // ushort elements
            load16_lds(xbf  + (size_t)(rm0 + row) * DIM + k0 + scol_src, As + ldsoff);
            load16_lds(cbbf + (size_t)(cn0 + row) * DIM + k0 + scol_src, Bs + ldsoff);
        }
        __syncthreads();
#pragma unroll
        for (int kk = 0; kk < 2; ++kk) {
            bf16x8 af[4], bfr[4];
#pragma unroll
            for (int ii = 0; ii < 4; ii++) {
                int r = wy * 64 + ii * 16 + r16;
                int ch = (kk * 4 + q) ^ (r16 & 7);
                af[ii] = *(const bf16x8*)(As + r * 64 + ch * 8);
            }
#pragma unroll
            for (int jj = 0; jj < 4; jj++) {
                int c = wx * 64 + jj * 16 + r16;
                int ch = (kk * 4 + q) ^ (r16 & 7);
                bfr[jj] = *(const bf16x8*)(Bs + c * 64 + ch * 8);
            }
#pragma unroll
            for (int ii = 0; ii < 4; ii++)
#pragma unroll
                for (int jj = 0; jj < 4; jj++)
                    acc[ii][jj] = __builtin_amdgcn_mfma_f32_16x16x32_bf16(
                        af[ii], bfr[jj], acc[ii][jj], 0, 0, 0);
        }
        __syncthreads();
    }

    // Epilogue: C/D layout col=lane&15, row=q*4+reg. Reduce max over 32-col blocks.
#pragma unroll
    for (int ii = 0; ii < 4; ii++) {
#pragma unroll
        for (int jjp = 0; jjp < 2; jjp++) {
            float v[4];
#pragma unroll
            for (int r = 0; r < 4; r++)
                v[r] = fmaxf(acc[ii][2 * jjp][r], acc[ii][2 * jjp + 1][r]);
#pragma unroll
            for (int d = 1; d < 16; d <<= 1)
#pragma unroll
                for (int r = 0; r < 4; r++) v[r] = fmaxf(v[r], __shfl_xor(v[r], d));
            if (r16 == 0) {
                int blk = by * 4 + wx * 2 + jjp;
#pragma unroll
                for (int r = 0; r < 4; r++) {
                    int row = rm0 + wy * 64 + ii * 16 + q * 4 + r;
                    blockmax[(size_t)row * NBLK + blk] = v[r];
                }
            }
        }
    }
}

// ---------------------------------------------------------------------------
// Phase 2: exact argmax, lane-per-candidate (unchanged from R2).
// ---------------------------------------------------------------------------
__global__ __launch_bounds__(256)
void argmax_kernel(const float* __restrict__ x, const float* __restrict__ cb,
                   const float* __restrict__ blockmax, const double* __restrict__ inv_cnorm,
                   int* __restrict__ best_idx) {
    __shared__ float4 xs[4][64];
    const int w    = threadIdx.x >> 6;
    const int row  = blockIdx.x * 4 + w;
    const int lane = threadIdx.x & 63;

    xs[w][lane] = ((const float4*)(x + (size_t)row * DIM))[lane];

    float4 b4 = ((const float4*)(blockmax + (size_t)row * NBLK))[lane];
    float m = fmaxf(fmaxf(b4.x, b4.y), fmaxf(b4.z, b4.w));
    float rowmax = wave_max(m);
    float thr = rowmax - MARGIN;

    double best_s = -1e300;
    int best_i = 0x7fffffff;

    auto eval_pair = [&](int bA, int bB) {
        int n = -1;
        if (lane < 32) n = bA * 32 + lane;
        else if (bB >= 0) n = bB * 32 + (lane - 32);
        if (n >= 0) {
            const float4* crow = (const float4*)(cb + (size_t)n * DIM);
            double s0 = 0., s1 = 0., s2 = 0., s3 = 0.;
#pragma unroll 8
            for (int jj = 0; jj < 64; ++jj) {
                float4 xv = xs[w][jj];
                float4 cv = crow[jj];
                s0 = fma((double)xv.x, (double)cv.x, s0);
                s1 = fma((double)xv.y, (double)cv.y, s1);
                s2 = fma((double)xv.z, (double)cv.z, s2);
                s3 = fma((double)xv.w, (double)cv.w, s3);
            }
            double s = ((s0 + s1) + (s2 + s3)) * inv_cnorm[n];
            if (s > best_s || (s == best_s && n < best_i)) { best_s = s; best_i = n; }
        }
    };

    float bmv[4] = {b4.x, b4.y, b4.z, b4.w};
    int pend = -1;
#pragma unroll
    for (int j = 0; j < 4; j++) {
        unsigned long long mask = __ballot(bmv[j] >= thr);   // wave-uniform
        while (mask) {
            int src = __ffsll((unsigned long long)mask) - 1;
            mask &= mask - 1;
            int blk = src * 4 + j;
            if (pend < 0) pend = blk;
            else { eval_pair(pend, blk); pend = -1; }
        }
    }
    if (pend >= 0) eval_pair(pend, -1);

    for (int d = 1; d < 64; d <<= 1) {
        double os = __shfl_xor(best_s, d);
        int    oi = __shfl_xor(best_i, d);
        if (os > best_s || (os == best_s && oi < best_i)) { best_s = os; best_i = oi; }
    }
    if (lane == 0) best_idx[row] = best_i;
}

// ---------------------------------------------------------------------------
// Phase 3: gather + scalar + proj + x_q + commit-loss accumulation.
// ---------------------------------------------------------------------------
__global__ __launch_bounds__(256)
void finalize_kernel(const float* __restrict__ x, const float* __restrict__ cb,
                     const int* __restrict__ best_idx, float* __restrict__ out,
                     float* __restrict__ loss_acc) {
    __shared__ float lsum[4];
    int w    = threadIdx.x >> 6;
    int row  = blockIdx.x * 4 + w;
    int lane = threadIdx.x & 63;
    int idx  = best_idx[row];
    float4 xv = ((const float4*)(x + (size_t)row * DIM))[lane];
    float4 cv = ((const float4*)(cb + (size_t)idx * DIM))[lane];
    float dot = xv.x * cv.x + xv.y * cv.y + xv.z * cv.z + xv.w * cv.w;
    float nsq = cv.x * cv.x + cv.y * cv.y + cv.z * cv.z + cv.w * cv.w;
    float xsq = xv.x * xv.x + xv.y * xv.y + xv.z * xv.z + xv.w * xv.w;
    for (int d = 1; d < 64; d <<= 1) {
        dot += __shfl_xor(dot, d);
        nsq += __shfl_xor(nsq, d);
        xsq += __shfl_xor(xsq, d);
    }
    float scalar = dot / (nsq + 1e-8f);
    float4 pj = {scalar * cv.x, scalar * cv.y, scalar * cv.z, scalar * cv.w};
    ((float4*)(out + OUT_XQ + (size_t)row * DIM))[lane] = pj;

    float pn = fmaxf(sqrtf(scalar * scalar * nsq), 1e-8f);
    float xn = fmaxf(sqrtf(xsq), 1e-8f);
    float commit = (scalar * dot) / (pn * xn);
    if (lane == 0) {
        lsum[w] = 1.f - commit;
        out[OUT_IDX + row]  = (float)idx;
        out[OUT_SCAL + row] = scalar;
    }
    __syncthreads();
    if (threadIdx.x == 0)
        atomicAdd(loss_acc, lsum[0] + lsum[1] + lsum[2] + lsum[3]);
}

__global__ void loss_kernel(const float* __restrict__ loss_acc, float* __restrict__ out) {
    out[OUT_LOSS] = 0.25f * (*loss_acc) * (1.0f / 32768.0f);
}

// ---------------------------------------------------------------------------
extern "C" void kernel_launch(void* const* d_in, const int* in_sizes, int n_in,
                              void* d_out, int out_size, void* d_ws, size_t ws_size,
                              hipStream_t stream) {
    const float* x  = (const float*)d_in[0];
    const float* cb = (const float*)d_in[1];
    float* out = (float*)d_out;
    char*  ws  = (char*)d_ws;
    ushort* xbf      = (ushort*)(ws + WS_XBF);
    ushort* cbbf     = (ushort*)(ws + WS_CBBF);
    float*  blockmax = (float*)(ws + WS_BLOCKMAX);
    double* inv_cn   = (double*)(ws + WS_CNORM);
    int*    best_idx = (int*)(ws + WS_BESTIDX);
    float*  loss_acc = (float*)(ws + WS_LOSS);

    hipLaunchKernelGGL(prep_kernel, dim3((B_ROWS + N_CB) / 4), dim3(256), 0, stream,
                       x, cb, xbf, cbbf, inv_cn, loss_acc);
    hipLaunchKernelGGL(simmax_kernel, dim3(B_ROWS / 128, N_CB / 128), dim3(256), 0, stream,
                       xbf, cbbf, blockmax);
    hipLaunchKernelGGL(argmax_kernel, dim3(B_ROWS / 4), dim3(256), 0, stream,
                       x, cb, blockmax, inv_cn, best_idx);
    hipLaunchKernelGGL(finalize_kernel, dim3(B_ROWS / 4), dim3(256), 0, stream,
                       x, cb, best_idx, out, loss_acc);
    hipLaunchKernelGGL(loss_kernel, dim3(1), dim3(1), 0, stream, loss_acc, out);
}

// Round 4
// 662.402 us; speedup vs baseline: 1.1947x; 1.0361x over previous
//
#include <hip/hip_runtime.h>
#include <hip/hip_bf16.h>
#include <cstdint>
#include <cstddef>

// Problem constants
#define B_ROWS 32768
#define DIM    256
#define N_CB   8192
#define NBLK   256          // 32-wide column blocks per row (8192/32)
#define MARGIN 8e-3f        // provable bound: 2 * 2^-8 * ||a||*||b|| = 7.8e-3 (RNE bf16)

typedef __bf16 bf16x8 __attribute__((ext_vector_type(8)));
typedef float  f32x4  __attribute__((ext_vector_type(4)));

// ---- workspace layout (bytes) ----
#define WS_XBF      ((size_t)0)                    // 32768*256*2 = 16 MB
#define WS_CBBF     ((size_t)16777216)             //  8192*256*2 =  4 MB
#define WS_BLOCKMAX ((size_t)20971520)             // 32768*256*4 = 32 MB
#define WS_CNORM    ((size_t)54525952)             //  8192*8     = 64 KB (inv norms, fp64)
#define WS_BESTIDX  ((size_t)54591488)             // 32768*4     = 128 KB
#define WS_LOSS     ((size_t)54722560)             // 4 B   (total ~54.7 MB)

// ---- output layout (floats, concatenated in return order) ----
#define OUT_XQ   ((size_t)0)
#define OUT_LOSS ((size_t)8388608)
#define OUT_IDX  ((size_t)8388609)
#define OUT_SCAL ((size_t)(8388609 + 32768))

__device__ inline double wave_sum_d(double v){ for (int d = 1; d < 64; d <<= 1) v += __shfl_xor(v, d); return v; }
__device__ inline float wave_max(float v)   { for (int d = 1; d < 64; d <<= 1) v = fmaxf(v, __shfl_xor(v, d)); return v; }

// Manual round-to-nearest-even f32 -> bf16 so the filter error bound holds (|rel| <= 2^-9).
__device__ inline ushort f2bf(float f) {
    unsigned u = __float_as_uint(f);
    unsigned r = (u + 0x7fffu + ((u >> 16) & 1u)) >> 16;
    return (ushort)r;
}

__device__ inline void load16_lds(const void* g, void* l) {
    __builtin_amdgcn_global_load_lds(
        (const __attribute__((address_space(1))) unsigned int*)g,
        (__attribute__((address_space(3))) unsigned int*)l, 16, 0, 0);
}

// ---------------------------------------------------------------------------
// Phase 0: per-row L2 norms, bf16 normalized copies, fp64 inverse codebook norms.
// ---------------------------------------------------------------------------
__global__ __launch_bounds__(256)
void prep_kernel(const float* __restrict__ x, const float* __restrict__ cb,
                 ushort* __restrict__ xbf, ushort* __restrict__ cbbf,
                 double* __restrict__ inv_cnorm, float* __restrict__ loss_acc) {
    if (blockIdx.x == 0 && threadIdx.x == 0) *loss_acc = 0.f;
    int gw   = blockIdx.x * 4 + (threadIdx.x >> 6);
    int lane = threadIdx.x & 63;
    bool is_cb = gw >= B_ROWS;
    int row  = is_cb ? gw - B_ROWS : gw;
    const float* src = is_cb ? cb + (size_t)row * DIM : x + (size_t)row * DIM;
    ushort*      dst = is_cb ? cbbf + (size_t)row * DIM : xbf + (size_t)row * DIM;

    float4 v = ((const float4*)src)[lane];
    double ss = (double)v.x * v.x + (double)v.y * v.y + (double)v.z * v.z + (double)v.w * v.w;
    ss = wave_sum_d(ss);
    float inv = 1.f / fmaxf(sqrtf((float)ss), 1e-12f);
    ushort4 o;
    o.x = f2bf(v.x * inv); o.y = f2bf(v.y * inv);
    o.z = f2bf(v.z * inv); o.w = f2bf(v.w * inv);
    ((ushort4*)dst)[lane] = o;
    if (is_cb && lane == 0) inv_cnorm[row] = 1.0 / sqrt(ss);
}

// ---------------------------------------------------------------------------
// Phase 1: bf16 MFMA "GEMM" producing per-(row, 32-col-block) sim maxes.
// m97 structure + XOR-swizzled LDS (R3): chunk-position p of row r holds
// global 16B-chunk (p ^ (r&7)); fragment ds_read_b128 is conflict-free.
// ---------------------------------------------------------------------------
__global__ __launch_bounds__(256, 2)
void simmax_kernel(const ushort* __restrict__ xbf, const ushort* __restrict__ cbbf,
                   float* __restrict__ blockmax) {
    __shared__ __align__(16) ushort As[128 * 64];
    __shared__ __align__(16) ushort Bs[128 * 64];
    const int t   = threadIdx.x;
    const int rm0 = blockIdx.x * 128;          // row-tile   (x rows)
    const int by  = blockIdx.y;
    const int cn0 = by * 128;                  // col-tile   (codebook rows)
    const int wid = t >> 6, lane = t & 63;
    const int wy = wid >> 1, wx = wid & 1;
    const int q = lane >> 4, r16 = lane & 15;

    f32x4 acc[4][4];
#pragma unroll
    for (int i = 0; i < 4; i++)
#pragma unroll
        for (int j = 0; j < 4; j++) acc[i][j] = (f32x4){0.f, 0.f, 0.f, 0.f};

    const int srow     = t >> 3;                            // row within 32-row group
    const int cpos     = t & 7;                             // LDS chunk position
    const int csrc     = cpos ^ (srow & 7);                 // swizzled global chunk
    const int scol_src = csrc * 8;                          // global element offset
    const int scol_lds = cpos * 8;                          // LDS element offset

#pragma unroll
    for (int ks = 0; ks < 4; ++ks) {
        const int k0 = ks * 64;
#pragma unroll
        for (int it = 0; it < 4; ++it) {
            const int row = it * 32 + srow;
            const int ldsoff = row * 64 + scol_lds;          // ushort elements
            load16_lds(xbf  + (size_t)(rm0 + row) * DIM + k0 + scol_src, As + ldsoff);
            load16_lds(cbbf + (size_t)(cn0 + row) * DIM + k0 + scol_src, Bs + ldsoff);
        }
        __syncthreads();
#pragma unroll
        for (int kk = 0; kk < 2; ++kk) {
            bf16x8 af[4], bfr[4];
#pragma unroll
            for (int ii = 0; ii < 4; ii++) {
                int r = wy * 64 + ii * 16 + r16;
                int ch = (kk * 4 + q) ^ (r16 & 7);
                af[ii] = *(const bf16x8*)(As + r * 64 + ch * 8);
            }
#pragma unroll
            for (int jj = 0; jj < 4; jj++) {
                int c = wx * 64 + jj * 16 + r16;
                int ch = (kk * 4 + q) ^ (r16 & 7);
                bfr[jj] = *(const bf16x8*)(Bs + c * 64 + ch * 8);
            }
#pragma unroll
            for (int ii = 0; ii < 4; ii++)
#pragma unroll
                for (int jj = 0; jj < 4; jj++)
                    acc[ii][jj] = __builtin_amdgcn_mfma_f32_16x16x32_bf16(
                        af[ii], bfr[jj], acc[ii][jj], 0, 0, 0);
        }
        __syncthreads();
    }

    // Epilogue: C/D layout col=lane&15, row=q*4+reg. Reduce max over 32-col blocks.
#pragma unroll
    for (int ii = 0; ii < 4; ii++) {
#pragma unroll
        for (int jjp = 0; jjp < 2; jjp++) {
            float v[4];
#pragma unroll
            for (int r = 0; r < 4; r++)
                v[r] = fmaxf(acc[ii][2 * jjp][r], acc[ii][2 * jjp + 1][r]);
#pragma unroll
            for (int d = 1; d < 16; d <<= 1)
#pragma unroll
                for (int r = 0; r < 4; r++) v[r] = fmaxf(v[r], __shfl_xor(v[r], d));
            if (r16 == 0) {
                int blk = by * 4 + wx * 2 + jjp;
#pragma unroll
                for (int r = 0; r < 4; r++) {
                    int row = rm0 + wy * 64 + ii * 16 + q * 4 + r;
                    blockmax[(size_t)row * NBLK + blk] = v[r];
                }
            }
        }
    }
}

// ---------------------------------------------------------------------------
// Phase 2: exact argmax, 8-lanes-per-candidate COALESCED gather.
// One wave per row. lane = c*8+e: 8 candidates in flight, each read as
// contiguous 128B segments (8 segments/instr vs 64 divergent lines in R2/R3).
// fp64 dot on ORIGINAL fp32 data x fp64 inv codebook norm (x-row norm is a
// positive row-constant and cannot change the argmax). Deterministic
// reduction order: 4 in-lane accumulators over jj, then xor-tree over e.
// ---------------------------------------------------------------------------
__global__ __launch_bounds__(256)
void argmax_kernel(const float* __restrict__ x, const float* __restrict__ cb,
                   const float* __restrict__ blockmax, const double* __restrict__ inv_cnorm,
                   int* __restrict__ best_idx) {
    const int row  = blockIdx.x * 4 + (threadIdx.x >> 6);
    const int lane = threadIdx.x & 63;
    const int c    = lane >> 3;   // candidate slot within group of 8
    const int e    = lane & 7;    // element-group within candidate row

    float4 b4 = ((const float4*)(blockmax + (size_t)row * NBLK))[lane];
    float m = fmaxf(fmaxf(b4.x, b4.y), fmaxf(b4.z, b4.w));
    float rowmax = wave_max(m);
    float thr = rowmax - MARGIN;

    // preload this row's x into registers: lane e covers chunks jj*8+e
    const float4* xrow = (const float4*)(x + (size_t)row * DIM);
    float4 xr[8];
#pragma unroll
    for (int jj = 0; jj < 8; ++jj) xr[jj] = xrow[jj * 8 + e];

    double best_s = -1e300;
    int best_i = 0x7fffffff;

    float bmv[4] = {b4.x, b4.y, b4.z, b4.w};
#pragma unroll
    for (int j = 0; j < 4; j++) {
        unsigned long long mask = __ballot(bmv[j] >= thr);   // wave-uniform
        while (mask) {
            int src = __ffsll((unsigned long long)mask) - 1;
            mask &= mask - 1;
            int blk = src * 4 + j;
#pragma unroll 1
            for (int sub = 0; sub < 4; ++sub) {
                int n = blk * 32 + sub * 8 + c;
                const float4* crow = (const float4*)(cb + (size_t)n * DIM);
                double s0 = 0., s1 = 0., s2 = 0., s3 = 0.;
#pragma unroll
                for (int jj = 0; jj < 8; ++jj) {
                    float4 cv = crow[jj * 8 + e];   // lanes e=0..7: 128B contiguous
                    float4 xv = xr[jj];
                    s0 = fma((double)xv.x, (double)cv.x, s0);
                    s1 = fma((double)xv.y, (double)cv.y, s1);
                    s2 = fma((double)xv.z, (double)cv.z, s2);
                    s3 = fma((double)xv.w, (double)cv.w, s3);
                }
                double s = (s0 + s1) + (s2 + s3);
                s += __shfl_xor(s, 1);
                s += __shfl_xor(s, 2);
                s += __shfl_xor(s, 4);
                s *= inv_cnorm[n];
                if (e == 0 && (s > best_s || (s == best_s && n < best_i))) {
                    best_s = s; best_i = n;
                }
            }
        }
    }

    // wave argmax (value desc, index asc tiebreak); non-e0 lanes hold -1e300
    for (int d = 1; d < 64; d <<= 1) {
        double os = __shfl_xor(best_s, d);
        int    oi = __shfl_xor(best_i, d);
        if (os > best_s || (os == best_s && oi < best_i)) { best_s = os; best_i = oi; }
    }
    if (lane == 0) best_idx[row] = best_i;
}

// ---------------------------------------------------------------------------
// Phase 3: gather + scalar + proj + x_q + commit-loss accumulation.
// ---------------------------------------------------------------------------
__global__ __launch_bounds__(256)
void finalize_kernel(const float* __restrict__ x, const float* __restrict__ cb,
                     const int* __restrict__ best_idx, float* __restrict__ out,
                     float* __restrict__ loss_acc) {
    __shared__ float lsum[4];
    int w    = threadIdx.x >> 6;
    int row  = blockIdx.x * 4 + w;
    int lane = threadIdx.x & 63;
    int idx  = best_idx[row];
    float4 xv = ((const float4*)(x + (size_t)row * DIM))[lane];
    float4 cv = ((const float4*)(cb + (size_t)idx * DIM))[lane];
    float dot = xv.x * cv.x + xv.y * cv.y + xv.z * cv.z + xv.w * cv.w;
    float nsq = cv.x * cv.x + cv.y * cv.y + cv.z * cv.z + cv.w * cv.w;
    float xsq = xv.x * xv.x + xv.y * xv.y + xv.z * xv.z + xv.w * xv.w;
    for (int d = 1; d < 64; d <<= 1) {
        dot += __shfl_xor(dot, d);
        nsq += __shfl_xor(nsq, d);
        xsq += __shfl_xor(xsq, d);
    }
    float scalar = dot / (nsq + 1e-8f);
    float4 pj = {scalar * cv.x, scalar * cv.y, scalar * cv.z, scalar * cv.w};
    ((float4*)(out + OUT_XQ + (size_t)row * DIM))[lane] = pj;

    float pn = fmaxf(sqrtf(scalar * scalar * nsq), 1e-8f);
    float xn = fmaxf(sqrtf(xsq), 1e-8f);
    float commit = (scalar * dot) / (pn * xn);
    if (lane == 0) {
        lsum[w] = 1.f - commit;
        out[OUT_IDX + row]  = (float)idx;
        out[OUT_SCAL + row] = scalar;
    }
    __syncthreads();
    if (threadIdx.x == 0)
        atomicAdd(loss_acc, lsum[0] + lsum[1] + lsum[2] + lsum[3]);
}

__global__ void loss_kernel(const float* __restrict__ loss_acc, float* __restrict__ out) {
    out[OUT_LOSS] = 0.25f * (*loss_acc) * (1.0f / 32768.0f);
}

// ---------------------------------------------------------------------------
extern "C" void kernel_launch(void* const* d_in, const int* in_sizes, int n_in,
                              void* d_out, int out_size, void* d_ws, size_t ws_size,
                              hipStream_t stream) {
    const float* x  = (const float*)d_in[0];
    const float* cb = (const float*)d_in[1];
    float* out = (float*)d_out;
    char*  ws  = (char*)d_ws;
    ushort* xbf      = (ushort*)(ws + WS_XBF);
    ushort* cbbf     = (ushort*)(ws + WS_CBBF);
    float*  blockmax = (float*)(ws + WS_BLOCKMAX);
    double* inv_cn   = (double*)(ws + WS_CNORM);
    int*    best_idx = (int*)(ws + WS_BESTIDX);
    float*  loss_acc = (float*)(ws + WS_LOSS);

    hipLaunchKernelGGL(prep_kernel, dim3((B_ROWS + N_CB) / 4), dim3(256), 0, stream,
                       x, cb, xbf, cbbf, inv_cn, loss_acc);
    hipLaunchKernelGGL(simmax_kernel, dim3(B_ROWS / 128, N_CB / 128), dim3(256), 0, stream,
                       xbf, cbbf, blockmax);
    hipLaunchKernelGGL(argmax_kernel, dim3(B_ROWS / 4), dim3(256), 0, stream,
                       x, cb, blockmax, inv_cn, best_idx);
    hipLaunchKernelGGL(finalize_kernel, dim3(B_ROWS / 4), dim3(256), 0, stream,
                       x, cb, best_idx, out, loss_acc);
    hipLaunchKernelGGL(loss_kernel, dim3(1), dim3(1), 0, stream, loss_acc, out);
}

// Round 5
// 559.092 us; speedup vs baseline: 1.4154x; 1.1848x over previous
//
#include <hip/hip_runtime.h>
#include <hip/hip_bf16.h>
#include <hip/hip_fp16.h>
#include <cstdint>
#include <cstddef>

// Problem constants
#define B_ROWS 32768
#define DIM    256
#define NBLK64 128          // 64-wide column blocks per row (8192/64)
#define CERT_M 3.0e-3f      // > 2*eps_f; eps_f = fp16-filter sim err (<=1.13e-3 worst case)
#define PRE_M  3.0e-3f      // > eps_f + eps_v for the VALU fp16 prescan

typedef _Float16 f16x8 __attribute__((ext_vector_type(8)));
typedef float    f32x4 __attribute__((ext_vector_type(4)));
typedef unsigned short u16x8 __attribute__((ext_vector_type(8)));

// ---- workspace layout (bytes) ----
#define WS_XBF     ((size_t)0)                    // 32768*256*2 = 16 MB (f16 normalized x)
#define WS_CBBF    ((size_t)16777216)             //  8192*256*2 =  4 MB (f16 normalized cb)
#define WS_TOPINFO ((size_t)20971520)             // 32768*128*8 = 32 MB {f16 v1, f16 v2, u16 arg}
#define WS_CNORM   ((size_t)54525952)             //  8192*8     = 64 KB (fp64 inverse norms)
#define WS_BESTIDX ((size_t)54591488)             // 32768*4     = 128 KB
#define WS_LOSS    ((size_t)54722560)             // 4 B   (total ~54.7 MB)

// ---- output layout (floats, concatenated in return order) ----
#define OUT_XQ   ((size_t)0)
#define OUT_LOSS ((size_t)8388608)
#define OUT_IDX  ((size_t)8388609)
#define OUT_SCAL ((size_t)(8388609 + 32768))

__device__ inline double wave_sum_d(double v){ for (int d = 1; d < 64; d <<= 1) v += __shfl_xor(v, d); return v; }
__device__ inline unsigned umax_(unsigned a, unsigned b){ return a > b ? a : b; }

// order-preserving key for f16 bit patterns (no NaNs here)
__device__ inline ushort f16key(ushort b){ return (b & 0x8000) ? (ushort)(~b) : (ushort)(b | 0x8000); }
__device__ inline ushort keyf16(ushort k){ return (k & 0x8000) ? (ushort)(k & 0x7FFF) : (ushort)(~k); }
__device__ inline float  keyval(unsigned k16){ return __half2float(__ushort_as_half(keyf16((ushort)k16))); }

__device__ inline void load16_lds(const void* g, void* l) {
    __builtin_amdgcn_global_load_lds(
        (const __attribute__((address_space(1))) unsigned int*)g,
        (__attribute__((address_space(3))) unsigned int*)l, 16, 0, 0);
}

// ---------------------------------------------------------------------------
// Phase 0: per-row L2 norms, f16 (RNE) normalized copies, fp64 inverse norms.
// One wave per row; rows [0,32768) = x, [32768, 40960) = codebook.
// ---------------------------------------------------------------------------
__global__ __launch_bounds__(256)
void prep_kernel(const float* __restrict__ x, const float* __restrict__ cb,
                 ushort* __restrict__ xbf, ushort* __restrict__ cbbf,
                 double* __restrict__ inv_cnorm, float* __restrict__ loss_acc) {
    if (blockIdx.x == 0 && threadIdx.x == 0) *loss_acc = 0.f;
    int gw   = blockIdx.x * 4 + (threadIdx.x >> 6);
    int lane = threadIdx.x & 63;
    bool is_cb = gw >= B_ROWS;
    int row  = is_cb ? gw - B_ROWS : gw;
    const float* src = is_cb ? cb + (size_t)row * DIM : x + (size_t)row * DIM;
    ushort*      dst = is_cb ? cbbf + (size_t)row * DIM : xbf + (size_t)row * DIM;

    float4 v = ((const float4*)src)[lane];
    double ss = (double)v.x * v.x + (double)v.y * v.y + (double)v.z * v.z + (double)v.w * v.w;
    ss = wave_sum_d(ss);
    float inv = 1.f / fmaxf(sqrtf((float)ss), 1e-12f);
    ushort4 o;
    o.x = __half_as_ushort(__float2half(v.x * inv));
    o.y = __half_as_ushort(__float2half(v.y * inv));
    o.z = __half_as_ushort(__float2half(v.z * inv));
    o.w = __half_as_ushort(__float2half(v.w * inv));
    ((ushort4*)dst)[lane] = o;
    if (is_cb && lane == 0) inv_cnorm[row] = 1.0 / sqrt(ss);
}

// ---------------------------------------------------------------------------
// Phase 1: f16 MFMA filter GEMM. m97 structure + XOR-swizzled LDS (R3).
// Epilogue: per (row, 64-col block) compute top1/top2 values (f16 keys,
// smallest-col tiebreak) + top1's global col; pack 8 B into topinfo.
// ---------------------------------------------------------------------------
__global__ __launch_bounds__(256, 2)
void simmax_kernel(const ushort* __restrict__ xbf, const ushort* __restrict__ cbbf,
                   unsigned long long* __restrict__ topinfo) {
    __shared__ __align__(16) ushort As[128 * 64];
    __shared__ __align__(16) ushort Bs[128 * 64];
    const int t   = threadIdx.x;
    const int rm0 = blockIdx.x * 128;          // row-tile   (x rows)
    const int by  = blockIdx.y;
    const int cn0 = by * 128;                  // col-tile   (codebook rows)
    const int wid = t >> 6, lane = t & 63;
    const int wy = wid >> 1, wx = wid & 1;
    const int q = lane >> 4, r16 = lane & 15;

    f32x4 acc[4][4];
#pragma unroll
    for (int i = 0; i < 4; i++)
#pragma unroll
        for (int j = 0; j < 4; j++) acc[i][j] = (f32x4){0.f, 0.f, 0.f, 0.f};

    const int srow     = t >> 3;
    const int cpos     = t & 7;
    const int csrc     = cpos ^ (srow & 7);
    const int scol_src = csrc * 8;
    const int scol_lds = cpos * 8;

#pragma unroll
    for (int ks = 0; ks < 4; ++ks) {
        const int k0 = ks * 64;
#pragma unroll
        for (int it = 0; it < 4; ++it) {
            const int row = it * 32 + srow;
            const int ldsoff = row * 64 + scol_lds;
            load16_lds(xbf  + (size_t)(rm0 + row) * DIM + k0 + scol_src, As + ldsoff);
            load16_lds(cbbf + (size_t)(cn0 + row) * DIM + k0 + scol_src, Bs + ldsoff);
        }
        __syncthreads();
#pragma unroll
        for (int kk = 0; kk < 2; ++kk) {
            f16x8 af[4], bfr[4];
#pragma unroll
            for (int ii = 0; ii < 4; ii++) {
                int r = wy * 64 + ii * 16 + r16;
                int ch = (kk * 4 + q) ^ (r16 & 7);
                af[ii] = *(const f16x8*)(As + r * 64 + ch * 8);
            }
#pragma unroll
            for (int jj = 0; jj < 4; jj++) {
                int c = wx * 64 + jj * 16 + r16;
                int ch = (kk * 4 + q) ^ (r16 & 7);
                bfr[jj] = *(const f16x8*)(Bs + c * 64 + ch * 8);
            }
#pragma unroll
            for (int ii = 0; ii < 4; ii++)
#pragma unroll
                for (int jj = 0; jj < 4; jj++)
                    acc[ii][jj] = __builtin_amdgcn_mfma_f32_16x16x32_f16(
                        af[ii], bfr[jj], acc[ii][jj], 0, 0, 0);
        }
        __syncthreads();
    }

    // Epilogue. C/D layout: row_local = wy*64 + ii*16 + q*4 + reg, col_local =
    // jj*16 + r16. Each wave quadrant covers exactly one 64-col block.
    const int blockglob = by * 2 + wx;
#pragma unroll
    for (int ii = 0; ii < 4; ii++) {
#pragma unroll
        for (int r = 0; r < 4; r++) {
            unsigned key[4];
#pragma unroll
            for (int jj = 0; jj < 4; jj++) {
                ushort hb = __half_as_ushort(__float2half(acc[ii][jj][r]));
                int colg = cn0 + wx * 64 + jj * 16 + r16;
                key[jj] = ((unsigned)f16key(hb) << 16) | (unsigned)(8191 - colg);
            }
            unsigned m1 = umax_(umax_(key[0], key[1]), umax_(key[2], key[3]));
#pragma unroll
            for (int d = 1; d < 16; d <<= 1)
                m1 = umax_(m1, (unsigned)__shfl_xor((int)m1, d));
            unsigned a0 = (key[0] == m1) ? 0u : key[0];
            unsigned a1 = (key[1] == m1) ? 0u : key[1];
            unsigned a2 = (key[2] == m1) ? 0u : key[2];
            unsigned a3 = (key[3] == m1) ? 0u : key[3];
            unsigned m2 = umax_(umax_(a0, a1), umax_(a2, a3));
#pragma unroll
            for (int d = 1; d < 16; d <<= 1)
                m2 = umax_(m2, (unsigned)__shfl_xor((int)m2, d));
            if (r16 == 0) {
                int rowg = rm0 + wy * 64 + ii * 16 + q * 4 + r;
                ushort b1 = keyf16((ushort)(m1 >> 16));
                ushort b2 = keyf16((ushort)(m2 >> 16));
                unsigned arg1 = 8191 - (m1 & 0xFFFF);
                topinfo[(size_t)rowg * NBLK64 + blockglob] =
                    (unsigned long long)b1 |
                    ((unsigned long long)b2 << 16) |
                    ((unsigned long long)arg1 << 32);
            }
        }
    }
}

// ---------------------------------------------------------------------------
// Phase 2: decision kernel. One wave per row reads 128 packed block records.
// Certified (gap > CERT_M): emit stored arg, zero gather. Else: fp32 prescan
// of candidate blocks from L2-resident f16 codebook, exact fp64 eval of the
// few survivors from the ORIGINAL fp32 data (same formula/tiebreak as R2-R4).
// ---------------------------------------------------------------------------
__global__ __launch_bounds__(256)
void argmax_kernel(const float* __restrict__ x, const float* __restrict__ cb,
                   const ushort* __restrict__ xbf, const ushort* __restrict__ cbbf,
                   const unsigned long long* __restrict__ topinfo,
                   const double* __restrict__ inv_cnorm, int* __restrict__ best_idx) {
    const int row  = blockIdx.x * 4 + (threadIdx.x >> 6);
    const int lane = threadIdx.x & 63;

    ulonglong2 tt = ((const ulonglong2*)(topinfo + (size_t)row * NBLK64))[lane];
    unsigned long long tv[2] = {tt.x, tt.y};   // blocks 2*lane, 2*lane+1

    unsigned ok1[2], ok2[2], cand[2];
    float v1f[2];
#pragma unroll
    for (int s = 0; s < 2; ++s) {
        ushort b1 = (ushort)(tv[s] & 0xFFFF);
        ushort b2 = (ushort)((tv[s] >> 16) & 0xFFFF);
        unsigned arg = (unsigned)((tv[s] >> 32) & 0xFFFF);
        ok1[s] = f16key(b1);
        ok2[s] = f16key(b2);
        cand[s] = (ok1[s] << 16) | (8191 - arg);
        v1f[s] = __half2float(__ushort_as_half(b1));
    }

    unsigned W = umax_(cand[0], cand[1]);
    for (int d = 1; d < 64; d <<= 1) W = umax_(W, (unsigned)__shfl_xor((int)W, d));

    // runner = best stored value among everything except the winner element
    unsigned rv0 = (cand[0] == W) ? ok2[0] : ok1[0];
    unsigned rv1 = (cand[1] == W) ? ok2[1] : ok1[1];
    unsigned R = umax_(rv0, rv1);
    for (int d = 1; d < 64; d <<= 1) R = umax_(R, (unsigned)__shfl_xor((int)R, d));

    float v1w = keyval(W >> 16);
    float rvf = keyval(R);

    if (v1w - rvf > CERT_M) {                 // wave-uniform
        if (lane == 0) best_idx[row] = (int)(8191 - (W & 0xFFFF));
        return;
    }

    // ---- fallback: exact refine ----
    const int c = lane >> 3, e = lane & 7;
    float4 xv = ((const float4*)(x + (size_t)row * DIM))[lane];

    // f16 normalized x row, lane's 32-element chunk, as fp32
    float xh[32];
#pragma unroll
    for (int k4 = 0; k4 < 4; ++k4) {
        u16x8 hx = ((const u16x8*)(xbf + (size_t)row * DIM + e * 32))[k4];
#pragma unroll
        for (int j = 0; j < 8; ++j)
            xh[k4 * 8 + j] = __half2float(__ushort_as_half((ushort)hx[j]));
    }

    double best_s = -1e300;
    int best_i = 0x7fffffff;

    auto exact_eval = [&](int n) {
        float4 cv = ((const float4*)(cb + (size_t)n * DIM))[lane];
        double s = (double)xv.x * cv.x + (double)xv.y * cv.y +
                   (double)xv.z * cv.z + (double)xv.w * cv.w;
        s = wave_sum_d(s);
        s *= inv_cnorm[n];
        if (s > best_s || (s == best_s && n < best_i)) { best_s = s; best_i = n; }
    };

    const float thrblk = v1w - CERT_M;
    const float thrpre = v1w - PRE_M;
#pragma unroll
    for (int s = 0; s < 2; ++s) {
        unsigned long long bm = __ballot(v1f[s] >= thrblk);   // wave-uniform
        while (bm) {
            int src = __ffsll((unsigned long long)bm) - 1;
            bm &= bm - 1;
            int blk = src * 2 + s;
#pragma unroll 1
            for (int sub = 0; sub < 8; ++sub) {
                int n = blk * 64 + sub * 8 + c;
                float s0 = 0.f, s1 = 0.f, s2 = 0.f, s3 = 0.f;
#pragma unroll
                for (int k4 = 0; k4 < 4; ++k4) {
                    u16x8 ch = ((const u16x8*)(cbbf + (size_t)n * DIM + e * 32))[k4];
#pragma unroll
                    for (int j = 0; j < 8; ++j) {
                        float cf = __half2float(__ushort_as_half((ushort)ch[j]));
                        float xf = xh[k4 * 8 + j];
                        if ((j & 3) == 0) s0 = fmaf(xf, cf, s0);
                        else if ((j & 3) == 1) s1 = fmaf(xf, cf, s1);
                        else if ((j & 3) == 2) s2 = fmaf(xf, cf, s2);
                        else s3 = fmaf(xf, cf, s3);
                    }
                }
                float ps = (s0 + s1) + (s2 + s3);
                ps += __shfl_xor(ps, 1);
                ps += __shfl_xor(ps, 2);
                ps += __shfl_xor(ps, 4);
                unsigned long long sv = __ballot(e == 0 && ps >= thrpre);
                while (sv) {
                    int b = __ffsll((unsigned long long)sv) - 1;
                    sv &= sv - 1;
                    exact_eval(blk * 64 + sub * 8 + (b >> 3));
                }
            }
        }
    }
    if (lane == 0) best_idx[row] = best_i;
}

// ---------------------------------------------------------------------------
// Phase 3: gather + scalar + proj + x_q + commit-loss accumulation.
// ---------------------------------------------------------------------------
__global__ __launch_bounds__(256)
void finalize_kernel(const float* __restrict__ x, const float* __restrict__ cb,
                     const int* __restrict__ best_idx, float* __restrict__ out,
                     float* __restrict__ loss_acc) {
    __shared__ float lsum[4];
    int w    = threadIdx.x >> 6;
    int row  = blockIdx.x * 4 + w;
    int lane = threadIdx.x & 63;
    int idx  = best_idx[row];
    float4 xv = ((const float4*)(x + (size_t)row * DIM))[lane];
    float4 cv = ((const float4*)(cb + (size_t)idx * DIM))[lane];
    float dot = xv.x * cv.x + xv.y * cv.y + xv.z * cv.z + xv.w * cv.w;
    float nsq = cv.x * cv.x + cv.y * cv.y + cv.z * cv.z + cv.w * cv.w;
    float xsq = xv.x * xv.x + xv.y * xv.y + xv.z * xv.z + xv.w * xv.w;
    for (int d = 1; d < 64; d <<= 1) {
        dot += __shfl_xor(dot, d);
        nsq += __shfl_xor(nsq, d);
        xsq += __shfl_xor(xsq, d);
    }
    float scalar = dot / (nsq + 1e-8f);
    float4 pj = {scalar * cv.x, scalar * cv.y, scalar * cv.z, scalar * cv.w};
    ((float4*)(out + OUT_XQ + (size_t)row * DIM))[lane] = pj;

    float pn = fmaxf(sqrtf(scalar * scalar * nsq), 1e-8f);
    float xn = fmaxf(sqrtf(xsq), 1e-8f);
    float commit = (scalar * dot) / (pn * xn);
    if (lane == 0) {
        lsum[w] = 1.f - commit;
        out[OUT_IDX + row]  = (float)idx;
        out[OUT_SCAL + row] = scalar;
    }
    __syncthreads();
    if (threadIdx.x == 0)
        atomicAdd(loss_acc, lsum[0] + lsum[1] + lsum[2] + lsum[3]);
}

__global__ void loss_kernel(const float* __restrict__ loss_acc, float* __restrict__ out) {
    out[OUT_LOSS] = 0.25f * (*loss_acc) * (1.0f / 32768.0f);
}

// ---------------------------------------------------------------------------
extern "C" void kernel_launch(void* const* d_in, const int* in_sizes, int n_in,
                              void* d_out, int out_size, void* d_ws, size_t ws_size,
                              hipStream_t stream) {
    const float* x  = (const float*)d_in[0];
    const float* cb = (const float*)d_in[1];
    float* out = (float*)d_out;
    char*  ws  = (char*)d_ws;
    ushort* xbf    = (ushort*)(ws + WS_XBF);
    ushort* cbbf   = (ushort*)(ws + WS_CBBF);
    unsigned long long* topinfo = (unsigned long long*)(ws + WS_TOPINFO);
    double* inv_cn = (double*)(ws + WS_CNORM);
    int*    best_idx = (int*)(ws + WS_BESTIDX);
    float*  loss_acc = (float*)(ws + WS_LOSS);

    hipLaunchKernelGGL(prep_kernel, dim3((B_ROWS + 8192) / 4), dim3(256), 0, stream,
                       x, cb, xbf, cbbf, inv_cn, loss_acc);
    hipLaunchKernelGGL(simmax_kernel, dim3(B_ROWS / 128, 8192 / 128), dim3(256), 0, stream,
                       xbf, cbbf, topinfo);
    hipLaunchKernelGGL(argmax_kernel, dim3(B_ROWS / 4), dim3(256), 0, stream,
                       x, cb, xbf, cbbf, topinfo, inv_cn, best_idx);
    hipLaunchKernelGGL(finalize_kernel, dim3(B_ROWS / 4), dim3(256), 0, stream,
                       x, cb, best_idx, out, loss_acc);
    hipLaunchKernelGGL(loss_kernel, dim3(1), dim3(1), 0, stream, loss_acc, out);
}

// Round 6
// 413.873 us; speedup vs baseline: 1.9121x; 1.3509x over previous
//
#include <hip/hip_runtime.h>
#include <hip/hip_bf16.h>
#include <hip/hip_fp16.h>
#include <cstdint>
#include <cstddef>

// Problem constants
#define B_ROWS 32768
#define DIM    256
#define NBLK64 128          // 64-wide column blocks per row (8192/64)
#define CERT_M 3.0e-3f      // > 2*eps_f16 (2.26e-3) + key-truncation slack (3e-4)
#define PRE_M  3.0e-3f      // > eps_f16 + prescan eps

typedef _Float16 f16x8 __attribute__((ext_vector_type(8)));
typedef float    f32x4 __attribute__((ext_vector_type(4)));
typedef unsigned short u16x8 __attribute__((ext_vector_type(8)));

// ---- workspace layout (bytes) ----
#define WS_XBF     ((size_t)0)                    // 32768*256*2 = 16 MB (f16 normalized x)
#define WS_CBBF    ((size_t)16777216)             //  8192*256*2 =  4 MB (f16 normalized cb)
#define WS_TOPINFO ((size_t)20971520)             // 32768*128*8 = 32 MB {u32 k1, u32 k2}
#define WS_CNORM   ((size_t)54525952)             //  8192*8     = 64 KB (fp64 inverse norms)
#define WS_LOSS    ((size_t)54722560)             // 4 B

// ---- output layout (floats, concatenated in return order) ----
#define OUT_XQ   ((size_t)0)
#define OUT_LOSS ((size_t)8388608)
#define OUT_IDX  ((size_t)8388609)
#define OUT_SCAL ((size_t)(8388609 + 32768))

__device__ inline double wave_sum_d(double v){ for (int d = 1; d < 64; d <<= 1) v += __shfl_xor(v, d); return v; }
__device__ inline unsigned umax_(unsigned a, unsigned b){ return a > b ? a : b; }

// order-preserving f32 bit keys (no NaNs in this data)
__device__ inline unsigned okey(float f){
    unsigned u = __float_as_uint(f);
    return ((int)u < 0) ? ~u : (u | 0x80000000u);
}
__device__ inline float kinv(unsigned k){
    unsigned u = (k & 0x80000000u) ? (k & 0x7FFFFFFFu) : ~k;
    return __uint_as_float(u);
}

__device__ inline void load16_lds(const void* g, void* l) {
    __builtin_amdgcn_global_load_lds(
        (const __attribute__((address_space(1))) unsigned int*)g,
        (__attribute__((address_space(3))) unsigned int*)l, 16, 0, 0);
}

// ---------------------------------------------------------------------------
// Phase 0: per-row L2 norms, f16 (RNE) normalized copies, fp64 inverse norms.
// ---------------------------------------------------------------------------
__global__ __launch_bounds__(256)
void prep_kernel(const float* __restrict__ x, const float* __restrict__ cb,
                 ushort* __restrict__ xbf, ushort* __restrict__ cbbf,
                 double* __restrict__ inv_cnorm, float* __restrict__ loss_acc) {
    if (blockIdx.x == 0 && threadIdx.x == 0) *loss_acc = 0.f;
    int gw   = blockIdx.x * 4 + (threadIdx.x >> 6);
    int lane = threadIdx.x & 63;
    bool is_cb = gw >= B_ROWS;
    int row  = is_cb ? gw - B_ROWS : gw;
    const float* src = is_cb ? cb + (size_t)row * DIM : x + (size_t)row * DIM;
    ushort*      dst = is_cb ? cbbf + (size_t)row * DIM : xbf + (size_t)row * DIM;

    float4 v = ((const float4*)src)[lane];
    double ss = (double)v.x * v.x + (double)v.y * v.y + (double)v.z * v.z + (double)v.w * v.w;
    ss = wave_sum_d(ss);
    float inv = 1.f / fmaxf(sqrtf((float)ss), 1e-12f);
    ushort4 o;
    o.x = __half_as_ushort(__float2half(v.x * inv));
    o.y = __half_as_ushort(__float2half(v.y * inv));
    o.z = __half_as_ushort(__float2half(v.z * inv));
    o.w = __half_as_ushort(__float2half(v.w * inv));
    ((ushort4*)dst)[lane] = o;
    if (is_cb && lane == 0) inv_cnorm[row] = 1.0 / sqrt(ss);
}

// ---------------------------------------------------------------------------
// Phase 1: f16 MFMA filter GEMM, TRANSPOSED accumulation. mfma(cb_frag,
// x_frag) puts x-row at col=lane&15 (fixed per lane) and 16 cb-cols in-lane
// (ii*16 + q*4 + reg). Per-row top1/top2 over each 64-col block is then an
// in-lane integer-key tree + 2-shfl cross-q merge. Keys: order-preserving
// f32 bits truncated to 19 bits | (8191-col) in low 13 bits (unique keys,
// smallest-col tiebreak via umax).
// ---------------------------------------------------------------------------
__global__ __launch_bounds__(256, 2)
void simmax_kernel(const ushort* __restrict__ xbf, const ushort* __restrict__ cbbf,
                   uint2* __restrict__ topinfo) {
    __shared__ __align__(16) ushort As[128 * 64];
    __shared__ __align__(16) ushort Bs[128 * 64];
    const int t   = threadIdx.x;
    const int rm0 = blockIdx.x * 128;          // row-tile   (x rows)
    const int by  = blockIdx.y;
    const int cn0 = by * 128;                  // col-tile   (codebook rows)
    const int wid = t >> 6, lane = t & 63;
    const int wy = wid >> 1, wx = wid & 1;
    const int q = lane >> 4, r16 = lane & 15;

    f32x4 acc[4][4];   // [ii = cb 16-tile][jj = x 16-tile]
#pragma unroll
    for (int i = 0; i < 4; i++)
#pragma unroll
        for (int j = 0; j < 4; j++) acc[i][j] = (f32x4){0.f, 0.f, 0.f, 0.f};

    const int srow     = t >> 3;
    const int cpos     = t & 7;
    const int csrc     = cpos ^ (srow & 7);
    const int scol_src = csrc * 8;
    const int scol_lds = cpos * 8;

#pragma unroll
    for (int ks = 0; ks < 4; ++ks) {
        const int k0 = ks * 64;
#pragma unroll
        for (int it = 0; it < 4; ++it) {
            const int row = it * 32 + srow;
            const int ldsoff = row * 64 + scol_lds;
            load16_lds(xbf  + (size_t)(rm0 + row) * DIM + k0 + scol_src, As + ldsoff);
            load16_lds(cbbf + (size_t)(cn0 + row) * DIM + k0 + scol_src, Bs + ldsoff);
        }
        __syncthreads();
#pragma unroll
        for (int kk = 0; kk < 2; ++kk) {
            f16x8 af[4], bfr[4];
            const int ch = (kk * 4 + q) ^ (r16 & 7);
#pragma unroll
            for (int jj = 0; jj < 4; jj++) {
                int r = wy * 64 + jj * 16 + r16;
                af[jj] = *(const f16x8*)(As + r * 64 + ch * 8);
            }
#pragma unroll
            for (int ii = 0; ii < 4; ii++) {
                int c = wx * 64 + ii * 16 + r16;
                bfr[ii] = *(const f16x8*)(Bs + c * 64 + ch * 8);
            }
#pragma unroll
            for (int ii = 0; ii < 4; ii++)
#pragma unroll
                for (int jj = 0; jj < 4; jj++)
                    acc[ii][jj] = __builtin_amdgcn_mfma_f32_16x16x32_f16(
                        bfr[ii], af[jj], acc[ii][jj], 0, 0, 0);   // TRANSPOSED
        }
        __syncthreads();
    }

    // Epilogue: per jj (x 16-tile), this lane's x-row = wy*64+jj*16+r16.
    // 16 in-lane cb-col values: col = cn0 + wx*64 + ii*16 + q*4 + reg.
    const int blockglob = by * 2 + wx;
    const int colbase = 8191 - (cn0 + wx * 64 + q * 4);
#pragma unroll
    for (int jj = 0; jj < 4; jj++) {
        unsigned k[16];
#pragma unroll
        for (int ii = 0; ii < 4; ii++)
#pragma unroll
            for (int r = 0; r < 4; r++)
                k[ii * 4 + r] = (okey(acc[ii][jj][r]) & 0xFFFFE000u)
                              | (unsigned)(colbase - ii * 16 - r);
        unsigned m1 = k[0];
#pragma unroll
        for (int i = 1; i < 16; i++) m1 = umax_(m1, k[i]);
        unsigned m2 = 0;
#pragma unroll
        for (int i = 0; i < 16; i++) m2 = umax_(m2, (k[i] == m1) ? 0u : k[i]);
        // cross-q merge (keys globally unique)
#pragma unroll
        for (int d = 16; d < 64; d <<= 1) {
            unsigned o1 = (unsigned)__shfl_xor((int)m1, d);
            unsigned o2 = (unsigned)__shfl_xor((int)m2, d);
            unsigned lo = m1 < o1 ? m1 : o1;
            m2 = umax_(umax_(m2, o2), lo);
            m1 = umax_(m1, o1);
        }
        if (q == 0) {
            int rowg = rm0 + wy * 64 + jj * 16 + r16;
            topinfo[(size_t)rowg * NBLK64 + blockglob] = make_uint2(m1, m2);
        }
    }
}

// ---------------------------------------------------------------------------
// Phase 2 (fused decision + finalize). One wave per row.
// Certified (gap > CERT_M): stored arg, zero gather. Else: f32 prescan from
// L2-resident f16 codebook, exact fp64 eval of survivors from fp32 data
// (same formula/tiebreak as R2-R5). Then scalar/proj/x_q/commit inline.
// ---------------------------------------------------------------------------
__global__ __launch_bounds__(256)
void argmax_kernel(const float* __restrict__ x, const float* __restrict__ cb,
                   const ushort* __restrict__ xbf, const ushort* __restrict__ cbbf,
                   const uint2* __restrict__ topinfo,
                   const double* __restrict__ inv_cnorm,
                   float* __restrict__ out, float* __restrict__ loss_acc) {
    __shared__ float lsum[4];
    const int w    = threadIdx.x >> 6;
    const int row  = blockIdx.x * 4 + w;
    const int lane = threadIdx.x & 63;

    uint4 tt = ((const uint4*)(topinfo + (size_t)row * NBLK64))[lane]; // blocks 2*lane, 2*lane+1
    unsigned k1[2] = {tt.x, tt.z};
    unsigned k2[2] = {tt.y, tt.w};

    unsigned W = umax_(k1[0], k1[1]);
    for (int d = 1; d < 64; d <<= 1) W = umax_(W, (unsigned)__shfl_xor((int)W, d));
    unsigned R = umax_((k1[0] == W) ? k2[0] : k1[0], (k1[1] == W) ? k2[1] : k1[1]);
    for (int d = 1; d < 64; d <<= 1) R = umax_(R, (unsigned)__shfl_xor((int)R, d));

    float v1w = kinv(W & 0xFFFFE000u);
    float rvf = kinv(R & 0xFFFFE000u);

    float4 xv = ((const float4*)(x + (size_t)row * DIM))[lane];

    int best_i;
    if (v1w - rvf > CERT_M) {                 // wave-uniform
        best_i = 8191 - (int)(W & 0x1FFFu);
    } else {
        // ---- fallback: prescan + exact refine ----
        const int c = lane >> 3, e = lane & 7;
        float xh[32];
#pragma unroll
        for (int k4 = 0; k4 < 4; ++k4) {
            u16x8 hx = ((const u16x8*)(xbf + (size_t)row * DIM + e * 32))[k4];
#pragma unroll
            for (int j = 0; j < 8; ++j)
                xh[k4 * 8 + j] = __half2float(__ushort_as_half((ushort)hx[j]));
        }

        double best_s = -1e300;
        int bi = 0x7fffffff;
        auto exact_eval = [&](int n) {
            float4 cv = ((const float4*)(cb + (size_t)n * DIM))[lane];
            double s = (double)xv.x * cv.x + (double)xv.y * cv.y +
                       (double)xv.z * cv.z + (double)xv.w * cv.w;
            s = wave_sum_d(s);
            s *= inv_cnorm[n];
            if (s > best_s || (s == best_s && n < bi)) { best_s = s; bi = n; }
        };

        const float thrblk = v1w - CERT_M;
        const float thrpre = v1w - PRE_M;
        float v1f[2] = {kinv(k1[0] & 0xFFFFE000u), kinv(k1[1] & 0xFFFFE000u)};
#pragma unroll
        for (int s = 0; s < 2; ++s) {
            unsigned long long bm = __ballot(v1f[s] >= thrblk);   // wave-uniform
            while (bm) {
                int src = __ffsll((unsigned long long)bm) - 1;
                bm &= bm - 1;
                int blk = src * 2 + s;
#pragma unroll 1
                for (int sub = 0; sub < 8; ++sub) {
                    int n = blk * 64 + sub * 8 + c;
                    float s0 = 0.f, s1 = 0.f, s2 = 0.f, s3 = 0.f;
#pragma unroll
                    for (int k4 = 0; k4 < 4; ++k4) {
                        u16x8 chv = ((const u16x8*)(cbbf + (size_t)n * DIM + e * 32))[k4];
#pragma unroll
                        for (int j = 0; j < 8; ++j) {
                            float cf = __half2float(__ushort_as_half((ushort)chv[j]));
                            float xf = xh[k4 * 8 + j];
                            if ((j & 3) == 0) s0 = fmaf(xf, cf, s0);
                            else if ((j & 3) == 1) s1 = fmaf(xf, cf, s1);
                            else if ((j & 3) == 2) s2 = fmaf(xf, cf, s2);
                            else s3 = fmaf(xf, cf, s3);
                        }
                    }
                    float ps = (s0 + s1) + (s2 + s3);
                    ps += __shfl_xor(ps, 1);
                    ps += __shfl_xor(ps, 2);
                    ps += __shfl_xor(ps, 4);
                    unsigned long long sv = __ballot(e == 0 && ps >= thrpre);
                    while (sv) {
                        int b = __ffsll((unsigned long long)sv) - 1;
                        sv &= sv - 1;
                        exact_eval(blk * 64 + sub * 8 + (b >> 3));
                    }
                }
            }
        }
        // wave argmax reduce
        for (int d = 1; d < 64; d <<= 1) {
            double os = __shfl_xor(best_s, d);
            int    oi = __shfl_xor(bi, d);
            if (os > best_s || (os == best_s && oi < bi)) { best_s = os; bi = oi; }
        }
        best_i = bi;
    }

    // ---- fused finalize ----
    float4 cv = ((const float4*)(cb + (size_t)best_i * DIM))[lane];
    float dot = xv.x * cv.x + xv.y * cv.y + xv.z * cv.z + xv.w * cv.w;
    float nsq = cv.x * cv.x + cv.y * cv.y + cv.z * cv.z + cv.w * cv.w;
    float xsq = xv.x * xv.x + xv.y * xv.y + xv.z * xv.z + xv.w * xv.w;
    for (int d = 1; d < 64; d <<= 1) {
        dot += __shfl_xor(dot, d);
        nsq += __shfl_xor(nsq, d);
        xsq += __shfl_xor(xsq, d);
    }
    float scalar = dot / (nsq + 1e-8f);
    float4 pj = {scalar * cv.x, scalar * cv.y, scalar * cv.z, scalar * cv.w};
    ((float4*)(out + OUT_XQ + (size_t)row * DIM))[lane] = pj;

    float pn = fmaxf(sqrtf(scalar * scalar * nsq), 1e-8f);
    float xn = fmaxf(sqrtf(xsq), 1e-8f);
    float commit = (scalar * dot) / (pn * xn);
    if (lane == 0) {
        lsum[w] = 1.f - commit;
        out[OUT_IDX + row]  = (float)best_i;
        out[OUT_SCAL + row] = scalar;
    }
    __syncthreads();
    if (threadIdx.x == 0)
        atomicAdd(loss_acc, lsum[0] + lsum[1] + lsum[2] + lsum[3]);
}

__global__ void loss_kernel(const float* __restrict__ loss_acc, float* __restrict__ out) {
    out[OUT_LOSS] = 0.25f * (*loss_acc) * (1.0f / 32768.0f);
}

// ---------------------------------------------------------------------------
extern "C" void kernel_launch(void* const* d_in, const int* in_sizes, int n_in,
                              void* d_out, int out_size, void* d_ws, size_t ws_size,
                              hipStream_t stream) {
    const float* x  = (const float*)d_in[0];
    const float* cb = (const float*)d_in[1];
    float* out = (float*)d_out;
    char*  ws  = (char*)d_ws;
    ushort* xbf    = (ushort*)(ws + WS_XBF);
    ushort* cbbf   = (ushort*)(ws + WS_CBBF);
    uint2*  topinfo = (uint2*)(ws + WS_TOPINFO);
    double* inv_cn = (double*)(ws + WS_CNORM);
    float*  loss_acc = (float*)(ws + WS_LOSS);

    hipLaunchKernelGGL(prep_kernel, dim3((B_ROWS + 8192) / 4), dim3(256), 0, stream,
                       x, cb, xbf, cbbf, inv_cn, loss_acc);
    hipLaunchKernelGGL(simmax_kernel, dim3(B_ROWS / 128, 8192 / 128), dim3(256), 0, stream,
                       xbf, cbbf, topinfo);
    hipLaunchKernelGGL(argmax_kernel, dim3(B_ROWS / 4), dim3(256), 0, stream,
                       x, cb, xbf, cbbf, topinfo, inv_cn, out, loss_acc);
    hipLaunchKernelGGL(loss_kernel, dim3(1), dim3(1), 0, stream, loss_acc, out);
}